// Round 11
// baseline (1059.620 us; speedup 1.0000x reference)
//
#include <hip/hip_runtime.h>
#include <hip/hip_bf16.h>

typedef __attribute__((ext_vector_type(8))) short short8;
typedef __attribute__((ext_vector_type(4))) float f32x4;

#define D_DIM 256
#define G_DIM 256
#define NSEG 4096
#define BM 64

__device__ __forceinline__ unsigned f2bf_u(float f) {
  unsigned u = __builtin_bit_cast(unsigned, f);
  return (u + 0x7fffu + ((u >> 16) & 1u)) >> 16;   // RNE, inputs are finite
}
__device__ __forceinline__ unsigned pk_bf2(float a, float b) {
  __hip_bfloat162 h = __float22bfloat162_rn(float2{a, b});  // v_cvt_pk_bf16_f32
  unsigned r;
  __builtin_memcpy(&r, &h, 4);
  return r;
}

// 16-lane-group sum via DPP (VALU-only, no LDS pipe)
template <int CTRL>
__device__ __forceinline__ float dpp_add(float v) {
  int x = __builtin_bit_cast(int, v);
  int y = __builtin_amdgcn_update_dpp(0, x, CTRL, 0xF, 0xF, true);
  return v + __builtin_bit_cast(float, y);
}
__device__ __forceinline__ float row16_sum(float v) {
  v = dpp_add<0xB1>(v);   // quad_perm [1,0,3,2]  (xor 1)
  v = dpp_add<0x4E>(v);   // quad_perm [2,3,0,1]  (xor 2)
  v = dpp_add<0x124>(v);  // row_ror:4
  v = dpp_add<0x128>(v);  // row_ror:8
  return v;               // all 16 lanes of the row hold the sum
}

// ---- W/Wg -> bf16, transposed: Wc[j][k] = (j<256 ? W[k][j] : Wg[k][j-256]) ----
__global__ void wconv_kernel(const float* __restrict__ W, const float* __restrict__ Wg,
                             unsigned short* __restrict__ Wc) {
  int j = blockIdx.x;          // 0..511
  int k = threadIdx.x;         // 0..255
  float v = (j < 256) ? W[k * 256 + j] : Wg[k * 256 + (j - 256)];
  Wc[j * 256 + k] = (unsigned short)f2bf_u(v);
}

// ---- counts per segment via binary search (batch is sorted) ----
__global__ void count_kernel(const int* __restrict__ batch, int N, float* __restrict__ counts) {
  int g = blockIdx.x * blockDim.x + threadIdx.x;
  if (g >= NSEG) return;
  int lo = 0, hi = N;
  while (lo < hi) { int mid = (lo + hi) >> 1; if (batch[mid] < g) lo = mid + 1; else hi = mid; }
  int lo2 = lo, hi2 = N;
  while (lo2 < hi2) { int mid = (lo2 + hi2) >> 1; if (batch[mid] < g + 1) lo2 = mid + 1; else hi2 = mid; }
  counts[g] = (float)(lo2 - lo);
}

// ---- fused: dual GEMM (states|gates) -> softmax gate -> segment partial sums ----
// block: 64 rows x 512 cols, 8 waves; wave w owns cols [w*32,+32) of BOTH halves.
// R5 structure (15625 blocks, 1 tile each, in dispatch order -- frozen invariant)
// + HALF-TILE STAGE PIPELINE: stage rows 0-31; issue rows 32-63's global loads
// into regs (async); barrier; K-phase-1 (m=0,1 -- reads rows 0-31 only) runs over
// the in-flight loads; cvt+write half B; barrier; K-phase-2 (m=2,3; B-loads
// repeat same addrs -> L1-hot). Memory issue spans ~half the block wall instead
// of a short burst -> higher delivered x-stream BW (the R5 binder).
__global__ __launch_bounds__(512, 4) void fused_main(
    const float* __restrict__ x, const int* __restrict__ batch,
    const unsigned short* __restrict__ Wc,
    const float* __restrict__ bvec, const float* __restrict__ bgvec,
    float* __restrict__ seg, int N) {
  __shared__ __align__(16) char xs[32768];        // x tile [64][256] bf16, swizzled
  __shared__ __align__(16) float part[8][64];     // per-wave row partial sums
  __shared__ __align__(16) float sinv[64];        // 1/rowsum

  const int t = threadIdx.x;
  const int lane = t & 63;
  const int wid = t >> 6;                         // 0..7
  const int lr = lane & 15;
  const int lk = lane >> 4;
  const int cb = wid * 32;
  const long row0 = (long)blockIdx.x * BM;        // N % 64 == 0 (1e6 = 15625*64)

  const int srl = t >> 5;                         // 0..15 (row slot within 16-row group)
  const int skb = (t & 31) * 8;                   // float col base

  // ---- stage half A (rows 0..31): its 0,1 ----
#pragma unroll
  for (int it = 0; it < 2; ++it) {
    int rl = it * 16 + srl;
    const float4* p = (const float4*)(x + (row0 + rl) * D_DIM + skb);
    float4 v0 = p[0], v1 = p[1];
    uint4 pk;
    pk.x = pk_bf2(v0.x, v0.y);
    pk.y = pk_bf2(v0.z, v0.w);
    pk.z = pk_bf2(v1.x, v1.y);
    pk.w = pk_bf2(v1.z, v1.w);
    int byte = (rl * 512 + skb * 2) ^ ((rl & 7) << 4);
    *(uint4*)(xs + byte) = pk;
  }

  // ---- issue half-B loads (rows 32..63) into regs; no wait until after K-phase-1 ----
  float4 LB[2][2];
#pragma unroll
  for (int j = 0; j < 2; ++j) {
    int rl = (2 + j) * 16 + srl;
    const float4* p = (const float4*)(x + (row0 + rl) * D_DIM + skb);
    LB[j][0] = p[0];
    LB[j][1] = p[1];
  }

  __syncthreads();  // B1: half A visible

  // acc n: 0,1 = states cols cb..cb+32; 2,3 = gates cols cb..cb+32.
  f32x4 acc[4][4];
#pragma unroll
  for (int m = 0; m < 4; ++m)
#pragma unroll
    for (int n = 0; n < 4; ++n) acc[m][n] = (f32x4){0.f, 0.f, 0.f, 0.f};

  // ---- K phase 1: m = 0,1 (rows 0..31) ----
  __builtin_amdgcn_s_setprio(1);
#pragma unroll
  for (int kk = 0; kk < 8; ++kk) {
    const int k0 = kk * 32 + lk * 8;
    short8 a[2], bb[4];
#pragma unroll
    for (int n = 0; n < 4; ++n) {
      int col = (n < 2) ? (cb + n * 16 + lr) : (256 + cb + (n - 2) * 16 + lr);
      bb[n] = *(const short8*)(Wc + col * 256 + k0);
    }
#pragma unroll
    for (int m = 0; m < 2; ++m) {
      int row = m * 16 + lr;
      int byte = (row * 512 + k0 * 2) ^ ((row & 7) << 4);
      a[m] = *(const short8*)(xs + byte);
    }
#pragma unroll
    for (int m = 0; m < 2; ++m)
#pragma unroll
      for (int n = 0; n < 4; ++n)
        acc[m][n] = __builtin_amdgcn_mfma_f32_16x16x32_bf16(a[m], bb[n], acc[m][n], 0, 0, 0);
  }
  __builtin_amdgcn_s_setprio(0);

  // ---- convert + write half B (loads completed under K-phase-1) ----
#pragma unroll
  for (int j = 0; j < 2; ++j) {
    int rl = (2 + j) * 16 + srl;
    uint4 pk;
    pk.x = pk_bf2(LB[j][0].x, LB[j][0].y);
    pk.y = pk_bf2(LB[j][0].z, LB[j][0].w);
    pk.z = pk_bf2(LB[j][1].x, LB[j][1].y);
    pk.w = pk_bf2(LB[j][1].z, LB[j][1].w);
    int byte = (rl * 512 + skb * 2) ^ ((rl & 7) << 4);
    *(uint4*)(xs + byte) = pk;
  }
  __syncthreads();  // B2: half B visible

  // ---- K phase 2: m = 2,3 (rows 32..63); bb re-reads same addrs (L1-hot) ----
  __builtin_amdgcn_s_setprio(1);
#pragma unroll
  for (int kk = 0; kk < 8; ++kk) {
    const int k0 = kk * 32 + lk * 8;
    short8 a[2], bb[4];
#pragma unroll
    for (int n = 0; n < 4; ++n) {
      int col = (n < 2) ? (cb + n * 16 + lr) : (256 + cb + (n - 2) * 16 + lr);
      bb[n] = *(const short8*)(Wc + col * 256 + k0);
    }
#pragma unroll
    for (int m = 0; m < 2; ++m) {
      int row = (m + 2) * 16 + lr;
      int byte = (row * 512 + k0 * 2) ^ ((row & 7) << 4);
      a[m] = *(const short8*)(xs + byte);
    }
#pragma unroll
    for (int m = 0; m < 2; ++m)
#pragma unroll
      for (int n = 0; n < 4; ++n)
        acc[m + 2][n] = __builtin_amdgcn_mfma_f32_16x16x32_bf16(a[m], bb[n], acc[m + 2][n], 0, 0, 0);
  }
  __builtin_amdgcn_s_setprio(0);

  // early: batch ids for the segment epilogue (K-loop regs just died;
  // L2 latency hides under exp/rowsum/gating below)
  int rb[4][4];
#pragma unroll
  for (int m = 0; m < 4; ++m) {
    const int4 v = *(const int4*)(batch + row0 + m * 16 + lk * 4);
    rb[m][0] = v.x; rb[m][1] = v.y; rb[m][2] = v.z; rb[m][3] = v.w;
  }
  const int g0 = batch[row0];
  const int g1 = batch[row0 + BM - 1];

  // gates: e = exp(logit + bg) in fp32 regs (no max-sub: logits ~N(0,1), exp <= ~500)
  float bgv[2];
#pragma unroll
  for (int n = 0; n < 2; ++n) bgv[n] = bgvec[cb + n * 16 + lr];
#pragma unroll
  for (int m = 0; m < 4; ++m)
#pragma unroll
    for (int n = 2; n < 4; ++n)
#pragma unroll
      for (int q = 0; q < 4; ++q)
        acc[m][n][q] = __expf(acc[m][n][q] + bgv[n - 2]);

  // wave-local row sums over this wave's 32 gate cols:
  // C layout: row = m*16 + lk*4 + q, col = n*16 + lr. Reduce over n (regs) then lr (DPP).
#pragma unroll
  for (int m = 0; m < 4; ++m) {
    float s[4];
#pragma unroll
    for (int q = 0; q < 4; ++q) s[q] = row16_sum(acc[m][2][q] + acc[m][3][q]);
    if (lr == 0) {
#pragma unroll
      for (int q = 0; q < 4; ++q) part[wid][m * 16 + lk * 4 + q] = s[q];
    }
  }
  __syncthreads();  // B3
  if (wid == 0) {
    float v = part[0][lane] + part[1][lane] + part[2][lane] + part[3][lane] +
              part[4][lane] + part[5][lane] + part[6][lane] + part[7][lane];
    sinv[lane] = 1.0f / v;
  }
  __syncthreads();  // B4

  // gating: gated = (states + b) * e * sinv
  float bv[2];
#pragma unroll
  for (int n = 0; n < 2; ++n) bv[n] = bvec[cb + n * 16 + lr];
  f32x4 siv[4];
#pragma unroll
  for (int m = 0; m < 4; ++m) siv[m] = *(const f32x4*)(&sinv[m * 16 + lk * 4]);
#pragma unroll
  for (int m = 0; m < 4; ++m)
#pragma unroll
    for (int n = 0; n < 2; ++n)
#pragma unroll
      for (int q = 0; q < 4; ++q)
        acc[m][n][q] = (acc[m][n][q] + bv[n]) * acc[m][n + 2][q] * siv[m][q];

  // segment reduce: batch sorted -> tile spans [g0, g1] (typically 1-2 segments)
  for (int g = g0; g <= g1; ++g) {
    float p[2] = {0.f, 0.f};
#pragma unroll
    for (int m = 0; m < 4; ++m)
#pragma unroll
      for (int q = 0; q < 4; ++q) {
        bool hit = (rb[m][q] == g);
#pragma unroll
        for (int n = 0; n < 2; ++n) p[n] += hit ? acc[m][n][q] : 0.f;
      }
#pragma unroll
    for (int n = 0; n < 2; ++n) {
      p[n] += __shfl_xor(p[n], 16);
      p[n] += __shfl_xor(p[n], 32);
    }
    if (lane < 16) {
#pragma unroll
      for (int n = 0; n < 2; ++n)
        atomicAdd(seg + (long)g * G_DIM + cb + n * 16 + lane, p[n]);
    }
  }
}

// ---- out = (seg/max(cnt,1)) @ Wf + bf, in-place on d_out (block-local staging) ----
__global__ __launch_bounds__(256) void final_kernel(
    float* __restrict__ seg, const float* __restrict__ counts,
    const float* __restrict__ Wf, const float* __restrict__ bfv) {
  __shared__ float mlds[16][257];
  int g0 = blockIdx.x * 16;
  int t = threadIdx.x;
#pragma unroll
  for (int i = 0; i < 16; ++i) {
    float inv = 1.0f / fmaxf(counts[g0 + i], 1.0f);
    mlds[i][t] = seg[(g0 + i) * 256 + t] * inv;
  }
  __syncthreads();
  float a[16];
#pragma unroll
  for (int i = 0; i < 16; ++i) a[i] = 0.f;
  for (int k = 0; k < 256; ++k) {
    float w = Wf[k * 256 + t];
#pragma unroll
    for (int i = 0; i < 16; ++i) a[i] += mlds[i][k] * w;
  }
  float bfx = bfv[t];
#pragma unroll
  for (int i = 0; i < 16; ++i) seg[(g0 + i) * 256 + t] = a[i] + bfx;
}

extern "C" void kernel_launch(void* const* d_in, const int* in_sizes, int n_in,
                              void* d_out, int out_size, void* d_ws, size_t ws_size,
                              hipStream_t stream) {
  const float* x = (const float*)d_in[0];
  const int* batch = (const int*)d_in[1];
  const float* W = (const float*)d_in[2];
  const float* b = (const float*)d_in[3];
  const float* Wg = (const float*)d_in[4];
  const float* bg = (const float*)d_in[5];
  const float* Wf = (const float*)d_in[6];
  const float* bf = (const float*)d_in[7];
  const int N = in_sizes[0] / D_DIM;  // 1,000,000

  unsigned short* Wc = (unsigned short*)d_ws;              // 512*256*2 = 262144 B
  float* counts = (float*)((char*)d_ws + 262144);          // 4096*4 = 16384 B
  float* seg = (float*)d_out;                              // seg_sum scratch == output buffer

  (void)hipMemsetAsync(d_out, 0, (size_t)out_size * sizeof(float), stream);
  hipLaunchKernelGGL(wconv_kernel, dim3(512), dim3(256), 0, stream, W, Wg, Wc);
  hipLaunchKernelGGL(count_kernel, dim3(NSEG / 256), dim3(256), 0, stream, batch, N, counts);
  hipLaunchKernelGGL(fused_main, dim3(N / BM), dim3(512), 0, stream, x, batch, Wc, b, bg, seg, N);
  hipLaunchKernelGGL(final_kernel, dim3(NSEG / 16), dim3(256), 0, stream, seg, counts, Wf, bf);
}

// Round 12
// 632.240 us; speedup vs baseline: 1.6760x; 1.6760x over previous
//
#include <hip/hip_runtime.h>
#include <hip/hip_bf16.h>

typedef __attribute__((ext_vector_type(8))) short short8;
typedef __attribute__((ext_vector_type(4))) float f32x4;

#define D_DIM 256
#define G_DIM 256
#define NSEG 4096
#define BM 64

__device__ __forceinline__ unsigned f2bf_u(float f) {
  unsigned u = __builtin_bit_cast(unsigned, f);
  return (u + 0x7fffu + ((u >> 16) & 1u)) >> 16;   // RNE, inputs are finite
}
__device__ __forceinline__ unsigned pk_bf2(float a, float b) {
  __hip_bfloat162 h = __float22bfloat162_rn(float2{a, b});  // v_cvt_pk_bf16_f32
  unsigned r;
  __builtin_memcpy(&r, &h, 4);
  return r;
}

// 16-lane-group sum via DPP (VALU-only, no LDS pipe)
template <int CTRL>
__device__ __forceinline__ float dpp_add(float v) {
  int x = __builtin_bit_cast(int, v);
  int y = __builtin_amdgcn_update_dpp(0, x, CTRL, 0xF, 0xF, true);
  return v + __builtin_bit_cast(float, y);
}
__device__ __forceinline__ float row16_sum(float v) {
  v = dpp_add<0xB1>(v);   // quad_perm [1,0,3,2]  (xor 1)
  v = dpp_add<0x4E>(v);   // quad_perm [2,3,0,1]  (xor 2)
  v = dpp_add<0x124>(v);  // row_ror:4
  v = dpp_add<0x128>(v);  // row_ror:8
  return v;               // all 16 lanes of the row hold the sum
}

// ---- W/Wg -> bf16 transposed + zero seg/counts (replaces memset + count_kernel's zeroing) ----
__global__ void wconv_kernel(const float* __restrict__ W, const float* __restrict__ Wg,
                             unsigned short* __restrict__ Wc,
                             float* __restrict__ seg, float* __restrict__ counts) {
  int j = blockIdx.x;          // 0..511
  int k = threadIdx.x;         // 0..255
  float v = (j < 256) ? W[k * 256 + j] : Wg[k * 256 + (j - 256)];
  Wc[j * 256 + k] = (unsigned short)f2bf_u(v);
  // zero seg (4096*256 = 1,048,576 floats): 131072 threads x 2 float4
  const int tid = j * 256 + k;
  const float4 z = {0.f, 0.f, 0.f, 0.f};
  ((float4*)seg)[tid * 2] = z;
  ((float4*)seg)[tid * 2 + 1] = z;
  if (tid < 1024) ((float4*)counts)[tid] = z;   // 4096 floats
}

// ---- fused: dual GEMM (states|gates) -> softmax gate -> segment partial sums ----
// block: 64 rows x 512 cols, 8 waves of 64; wave w owns cols [w*32, w*32+32) of BOTH halves.
// R5 body (639us) verbatim, plus: per-segment row COUNT accumulated in the existing
// shfl reduce and atomically added by wave 0 (replaces the binary-search count_kernel,
// whose ~40-deep dependent-load chain was pure serial stream latency).
__global__ __launch_bounds__(512, 4) void fused_main(
    const float* __restrict__ x, const int* __restrict__ batch,
    const unsigned short* __restrict__ Wc,
    const float* __restrict__ bvec, const float* __restrict__ bgvec,
    float* __restrict__ seg, float* __restrict__ counts, int N) {
  __shared__ __align__(16) char xs[32768];        // x tile [64][256] bf16, swizzled
  __shared__ __align__(16) float part[8][64];     // per-wave row partial sums
  __shared__ __align__(16) float sinv[64];        // 1/rowsum

  const int t = threadIdx.x;
  const int lane = t & 63;
  const int wid = t >> 6;                         // 0..7
  const int lr = lane & 15;
  const int lk = lane >> 4;
  const long row0 = (long)blockIdx.x * BM;        // N % 64 == 0 (1e6 = 15625*64)

  // stage x tile [64][256] as bf16, swizzle: byte ^= (row&7)<<4   (4 iters x 512 thr)
#pragma unroll
  for (int it = 0; it < 4; ++it) {
    int rl = it * 16 + (t >> 5);
    int kb = (t & 31) * 8;
    const float4* p = (const float4*)(x + (row0 + rl) * D_DIM + kb);
    float4 v0 = p[0], v1 = p[1];
    uint4 pk;
    pk.x = pk_bf2(v0.x, v0.y);
    pk.y = pk_bf2(v0.z, v0.w);
    pk.z = pk_bf2(v1.x, v1.y);
    pk.w = pk_bf2(v1.z, v1.w);
    int byte = (rl * 512 + kb * 2) ^ ((rl & 7) << 4);
    *(uint4*)(xs + byte) = pk;
  }
  __syncthreads();

  // K-loop, fully unrolled; B-frags direct from global (Wc 256KB, L2-resident).
  // acc n: 0,1 = states cols cb..cb+32; 2,3 = gates cols cb..cb+32.
  f32x4 acc[4][4];
#pragma unroll
  for (int m = 0; m < 4; ++m)
#pragma unroll
    for (int n = 0; n < 4; ++n) acc[m][n] = (f32x4){0.f, 0.f, 0.f, 0.f};

  const int cb = wid * 32;
  __builtin_amdgcn_s_setprio(1);
#pragma unroll
  for (int kk = 0; kk < 8; ++kk) {
    const int k0 = kk * 32 + lk * 8;
    short8 a[4], bb[4];
#pragma unroll
    for (int n = 0; n < 4; ++n) {
      int col = (n < 2) ? (cb + n * 16 + lr) : (256 + cb + (n - 2) * 16 + lr);
      bb[n] = *(const short8*)(Wc + col * 256 + k0);
    }
#pragma unroll
    for (int m = 0; m < 4; ++m) {
      int row = m * 16 + lr;
      int byte = (row * 512 + k0 * 2) ^ ((row & 7) << 4);
      a[m] = *(const short8*)(xs + byte);
    }
#pragma unroll
    for (int m = 0; m < 4; ++m)
#pragma unroll
      for (int n = 0; n < 4; ++n)
        acc[m][n] = __builtin_amdgcn_mfma_f32_16x16x32_bf16(a[m], bb[n], acc[m][n], 0, 0, 0);
  }
  __builtin_amdgcn_s_setprio(0);

  // early: batch ids for the segment epilogue (a[]/bb[] just died -> regs free;
  // L2 latency hides under exp/rowsum/gating below)
  int rb[4][4];
#pragma unroll
  for (int m = 0; m < 4; ++m) {
    const int4 v = *(const int4*)(batch + row0 + m * 16 + lk * 4);
    rb[m][0] = v.x; rb[m][1] = v.y; rb[m][2] = v.z; rb[m][3] = v.w;
  }
  const int g0 = batch[row0];
  const int g1 = batch[row0 + BM - 1];

  // gates: e = exp(logit + bg) in fp32 regs (no max-sub: logits ~N(0,1), exp <= ~500)
  float bgv[2];
#pragma unroll
  for (int n = 0; n < 2; ++n) bgv[n] = bgvec[cb + n * 16 + lr];
#pragma unroll
  for (int m = 0; m < 4; ++m)
#pragma unroll
    for (int n = 2; n < 4; ++n)
#pragma unroll
      for (int q = 0; q < 4; ++q)
        acc[m][n][q] = __expf(acc[m][n][q] + bgv[n - 2]);

  // wave-local row sums over this wave's 32 gate cols:
  // C layout: row = m*16 + lk*4 + q, col = n*16 + lr. Reduce over n (regs) then lr (DPP).
#pragma unroll
  for (int m = 0; m < 4; ++m) {
    float s[4];
#pragma unroll
    for (int q = 0; q < 4; ++q) s[q] = row16_sum(acc[m][2][q] + acc[m][3][q]);
    if (lr == 0) {
#pragma unroll
      for (int q = 0; q < 4; ++q) part[wid][m * 16 + lk * 4 + q] = s[q];
    }
  }
  __syncthreads();
  if (wid == 0) {
    float v = part[0][lane] + part[1][lane] + part[2][lane] + part[3][lane] +
              part[4][lane] + part[5][lane] + part[6][lane] + part[7][lane];
    sinv[lane] = 1.0f / v;
  }
  __syncthreads();

  // gating: gated = (states + b) * e * sinv
  float bv[2];
#pragma unroll
  for (int n = 0; n < 2; ++n) bv[n] = bvec[cb + n * 16 + lr];
  f32x4 siv[4];
#pragma unroll
  for (int m = 0; m < 4; ++m) siv[m] = *(const f32x4*)(&sinv[m * 16 + lk * 4]);
#pragma unroll
  for (int m = 0; m < 4; ++m)
#pragma unroll
    for (int n = 0; n < 2; ++n)
#pragma unroll
      for (int q = 0; q < 4; ++q)
        acc[m][n][q] = (acc[m][n][q] + bv[n]) * acc[m][n + 2][q] * siv[m][q];

  // segment reduce: batch sorted -> tile spans [g0, g1] (typically 1-2 segments).
  // pc rides the same reduce: after xor16/32, pc = rows_in_g (identical across
  // waves since rb doesn't depend on wid) -> wave 0 lane 0 adds it to counts[g].
  for (int g = g0; g <= g1; ++g) {
    float p[2] = {0.f, 0.f};
    float pc = 0.f;
#pragma unroll
    for (int m = 0; m < 4; ++m)
#pragma unroll
      for (int q = 0; q < 4; ++q) {
        bool hit = (rb[m][q] == g);
        pc += hit ? 1.f : 0.f;
#pragma unroll
        for (int n = 0; n < 2; ++n) p[n] += hit ? acc[m][n][q] : 0.f;
      }
#pragma unroll
    for (int n = 0; n < 2; ++n) {
      p[n] += __shfl_xor(p[n], 16);
      p[n] += __shfl_xor(p[n], 32);
    }
    pc += __shfl_xor(pc, 16);
    pc += __shfl_xor(pc, 32);
    if (lane < 16) {
#pragma unroll
      for (int n = 0; n < 2; ++n)
        atomicAdd(seg + (long)g * G_DIM + cb + n * 16 + lane, p[n]);
    }
    if (wid == 0 && lane == 0) atomicAdd(counts + g, pc);
  }
}

// ---- out = (seg/max(cnt,1)) @ Wf + bf, in-place on d_out (block-local staging) ----
__global__ __launch_bounds__(256) void final_kernel(
    float* __restrict__ seg, const float* __restrict__ counts,
    const float* __restrict__ Wf, const float* __restrict__ bfv) {
  __shared__ float mlds[16][257];
  int g0 = blockIdx.x * 16;
  int t = threadIdx.x;
#pragma unroll
  for (int i = 0; i < 16; ++i) {
    float inv = 1.0f / fmaxf(counts[g0 + i], 1.0f);
    mlds[i][t] = seg[(g0 + i) * 256 + t] * inv;
  }
  __syncthreads();
  float a[16];
#pragma unroll
  for (int i = 0; i < 16; ++i) a[i] = 0.f;
  for (int k = 0; k < 256; ++k) {
    float w = Wf[k * 256 + t];
#pragma unroll
    for (int i = 0; i < 16; ++i) a[i] += mlds[i][k] * w;
  }
  float bfx = bfv[t];
#pragma unroll
  for (int i = 0; i < 16; ++i) seg[(g0 + i) * 256 + t] = a[i] + bfx;
}

extern "C" void kernel_launch(void* const* d_in, const int* in_sizes, int n_in,
                              void* d_out, int out_size, void* d_ws, size_t ws_size,
                              hipStream_t stream) {
  const float* x = (const float*)d_in[0];
  const int* batch = (const int*)d_in[1];
  const float* W = (const float*)d_in[2];
  const float* b = (const float*)d_in[3];
  const float* Wg = (const float*)d_in[4];
  const float* bg = (const float*)d_in[5];
  const float* Wf = (const float*)d_in[6];
  const float* bf = (const float*)d_in[7];
  const int N = in_sizes[0] / D_DIM;  // 1,000,000

  unsigned short* Wc = (unsigned short*)d_ws;              // 512*256*2 = 262144 B
  float* counts = (float*)((char*)d_ws + 262144);          // 4096*4 = 16384 B
  float* seg = (float*)d_out;                              // seg_sum scratch == output buffer

  hipLaunchKernelGGL(wconv_kernel, dim3(512), dim3(256), 0, stream, W, Wg, Wc, seg, counts);
  hipLaunchKernelGGL(fused_main, dim3(N / BM), dim3(512), 0, stream, x, batch, Wc, b, bg, seg,
                     counts, N);
  hipLaunchKernelGGL(final_kernel, dim3(NSEG / 16), dim3(256), 0, stream, seg, counts, Wf, bf);
}